// Round 1
// baseline (211.767 us; speedup 1.0000x reference)
//
#include <hip/hip_runtime.h>
#include <hip/hip_bf16.h>
#include <math.h>

#define BB 8
#define NN 2048
#define CC 128
#define DD 128

// ---------------- Kernel A: Wh = x @ W^T  (Wh[b,n,d] = sum_c x[b,n,c]*W[d,c])
__global__ __launch_bounds__(256) void wh_kernel(
    const float* __restrict__ x, const float* __restrict__ W,
    float* __restrict__ Wh)
{
    __shared__ float Wt[128 * 132];   // Wt[c][d], pad 132 keeps float4 rows 16B-aligned
    __shared__ float xs[32 * 128];
    const int tid = threadIdx.x;
    const int b  = blockIdx.y;
    const int n0 = blockIdx.x * 32;

    // load W transposed into LDS (coalesced global reads)
    #pragma unroll
    for (int k = 0; k < 16; ++k) {
        int g  = tid + 256 * k;           // 4096 float4 = 128x128
        int d  = g >> 5, c4 = g & 31;
        float4 wv = *(const float4*)&W[d * 128 + c4 * 4];
        Wt[(c4 * 4 + 0) * 132 + d] = wv.x;
        Wt[(c4 * 4 + 1) * 132 + d] = wv.y;
        Wt[(c4 * 4 + 2) * 132 + d] = wv.z;
        Wt[(c4 * 4 + 3) * 132 + d] = wv.w;
    }
    // load x tile (32 rows x 128)
    #pragma unroll
    for (int k = 0; k < 4; ++k) {
        int g = tid + 256 * k;            // 1024 float4
        int r = g >> 5, c4 = g & 31;
        *(float4*)&xs[r * 128 + c4 * 4] =
            *(const float4*)&x[(size_t)(b * NN + n0 + r) * CC + c4 * 4];
    }
    __syncthreads();

    const int rg   = tid >> 5;            // 0..7  -> rows rg*4..rg*4+3
    const int dcol = (tid & 31) * 4;      // 0..124
    float4 acc[4];
    #pragma unroll
    for (int r = 0; r < 4; ++r) acc[r] = make_float4(0.f, 0.f, 0.f, 0.f);

    for (int c = 0; c < 128; ++c) {
        float4 wv = *(const float4*)&Wt[c * 132 + dcol];
        #pragma unroll
        for (int r = 0; r < 4; ++r) {
            float xr = xs[(rg * 4 + r) * 128 + c];
            acc[r].x += xr * wv.x; acc[r].y += xr * wv.y;
            acc[r].z += xr * wv.z; acc[r].w += xr * wv.w;
        }
    }
    #pragma unroll
    for (int r = 0; r < 4; ++r) {
        *(float4*)&Wh[(size_t)(b * NN + n0 + rg * 4 + r) * DD + dcol] = acc[r];
    }
}

// ---------------- Kernel B: f1 = Wh@a1, f2 = Wh@a2
__global__ __launch_bounds__(256) void f12_kernel(
    const float* __restrict__ Wh, const float* __restrict__ a,
    float* __restrict__ f1, float* __restrict__ f2)
{
    __shared__ float sa[256];
    const int tid = threadIdx.x;
    sa[tid] = a[tid];
    __syncthreads();
    const int row = blockIdx.x * 64 + (tid >> 2);   // 4 threads per row
    const int q   = tid & 3;
    float p1 = 0.f, p2 = 0.f;
    #pragma unroll
    for (int k = 0; k < 8; ++k) {
        int c = q * 4 + k * 16;
        float4 v = *(const float4*)&Wh[(size_t)row * 128 + c];
        p1 += v.x * sa[c]       + v.y * sa[c + 1]       + v.z * sa[c + 2]       + v.w * sa[c + 3];
        p2 += v.x * sa[128 + c] + v.y * sa[128 + c + 1] + v.z * sa[128 + c + 2] + v.w * sa[128 + c + 3];
    }
    p1 += __shfl_down(p1, 2); p1 += __shfl_down(p1, 1);
    p2 += __shfl_down(p2, 2); p2 += __shfl_down(p2, 1);
    if (q == 0) { f1[row] = p1; f2[row] = p2; }
}

// ---------------- Kernel C: fused masked-softmax attention + PV + elu
// block = 256 thr, handles 32 output rows (i) x 128 d for one batch.
// No max-subtraction: scores bounded (|f1+f2| <~ 6) so exp() is safe in f32;
// softmax is shift-invariant -> matches reference.
__global__ __launch_bounds__(256) void gat_kernel(
    const float* __restrict__ Wh, const int* __restrict__ adj,
    const float* __restrict__ f1, const float* __restrict__ f2,
    float* __restrict__ out)
{
    __shared__ float Whs[64 * 128];   // 32 KB, j-chunk of Wh
    __shared__ float wT[64 * 37];     // wT[jj][ii], pad 37 -> conflict-free scatter writes
    __shared__ float f2s[NN];         // whole batch row of f2 (8 KB)
    __shared__ float f1s[32];
    __shared__ float Ss[32];

    const int tid = threadIdx.x;
    const int b   = blockIdx.y;
    const int i0  = blockIdx.x * 32;

    #pragma unroll
    for (int k = 0; k < 8; ++k) f2s[tid + 256 * k] = f2[b * NN + tid + 256 * k];
    if (tid < 32) f1s[tid] = f1[b * NN + i0 + tid];
    __syncthreads();

    const int gw   = tid >> 6;         // wave id 0..3
    const int lane = tid & 63;
    const int rg   = tid >> 5;         // matmul row group 0..7
    const int dcol = (tid & 31) * 4;

    float4 acc[4];
    #pragma unroll
    for (int r = 0; r < 4; ++r) acc[r] = make_float4(0.f, 0.f, 0.f, 0.f);
    float s_part[8];
    #pragma unroll
    for (int k = 0; k < 8; ++k) s_part[k] = 0.f;

    for (int jc = 0; jc < NN / 64; ++jc) {
        const int j0 = jc * 64;
        // load Wh j-tile 64x128 (coalesced float4)
        #pragma unroll
        for (int k = 0; k < 8; ++k) {
            int gg = tid + 256 * k;        // 2048 float4
            int jj = gg >> 5, c4 = gg & 31;
            *(float4*)&Whs[jj * 128 + c4 * 4] =
                *(const float4*)&Wh[(size_t)(b * NN + j0 + jj) * DD + c4 * 4];
        }
        // scores: thread owns column jj = tid&63, rows ii = gw + 4k
        {
            const int jj  = tid & 63;
            const float f2v = f2s[j0 + jj];
            #pragma unroll
            for (int k = 0; k < 8; ++k) {
                const int ii = gw + 4 * k;
                int   ad = adj[(size_t)(i0 + ii) * NN + j0 + jj];
                float e  = f1s[ii] + f2v;
                e = (e > 0.f) ? e : 0.2f * e;
                float w = (ad > 0) ? __expf(e) : 0.f;
                wT[jj * 37 + ii] = w;
                s_part[k] += w;
            }
        }
        __syncthreads();
        // PV: acc[r][d] += w[ii][jj] * Whs[jj][d]
        #pragma unroll 4
        for (int jj = 0; jj < 64; ++jj) {
            float4 whv = *(const float4*)&Whs[jj * 128 + dcol];
            #pragma unroll
            for (int r = 0; r < 4; ++r) {
                float wv = wT[jj * 37 + rg * 4 + r];   // half-wave broadcast
                acc[r].x += wv * whv.x; acc[r].y += wv * whv.y;
                acc[r].z += wv * whv.z; acc[r].w += wv * whv.w;
            }
        }
        __syncthreads();
    }

    // reduce row-sums: wave gw owns rows {gw, gw+4, ..., gw+28}
    #pragma unroll
    for (int k = 0; k < 8; ++k) {
        float v = s_part[k];
        #pragma unroll
        for (int off = 32; off > 0; off >>= 1) v += __shfl_xor(v, off);
        if (lane == 0) Ss[gw + 4 * k] = v;
    }
    __syncthreads();

    #pragma unroll
    for (int r = 0; r < 4; ++r) {
        const int row = rg * 4 + r;
        float inv = 1.0f / Ss[row];
        float4 h;
        h.x = acc[r].x * inv; h.y = acc[r].y * inv;
        h.z = acc[r].z * inv; h.w = acc[r].w * inv;
        h.x = (h.x > 0.f) ? h.x : expm1f(h.x);
        h.y = (h.y > 0.f) ? h.y : expm1f(h.y);
        h.z = (h.z > 0.f) ? h.z : expm1f(h.z);
        h.w = (h.w > 0.f) ? h.w : expm1f(h.w);
        *(float4*)&out[(size_t)(b * NN + i0 + row) * DD + dcol] = h;
    }
}

extern "C" void kernel_launch(void* const* d_in, const int* in_sizes, int n_in,
                              void* d_out, int out_size, void* d_ws, size_t ws_size,
                              hipStream_t stream) {
    const float* x   = (const float*)d_in[0];
    const int*   adj = (const int*)d_in[1];
    const float* W   = (const float*)d_in[2];
    const float* a   = (const float*)d_in[3];
    float* out = (float*)d_out;

    float* Wh = (float*)d_ws;                 // 8*2048*128 f32
    float* f1 = Wh + (size_t)BB * NN * DD;    // 8*2048
    float* f2 = f1 + (size_t)BB * NN;         // 8*2048

    wh_kernel <<<dim3(NN / 32, BB), 256, 0, stream>>>(x, W, Wh);
    f12_kernel<<<dim3(BB * NN / 64),  256, 0, stream>>>(Wh, a, f1, f2);
    gat_kernel<<<dim3(NN / 32, BB), 256, 0, stream>>>(Wh, adj, f1, f2, out);
}

// Round 2
// 77.947 us; speedup vs baseline: 2.7168x; 2.7168x over previous
//
#include <hip/hip_runtime.h>
#include <hip/hip_bf16.h>
#include <math.h>

#define BB 8
#define NN 2048
#define CC 128
#define DD 128

typedef __attribute__((ext_vector_type(8))) short short8;
typedef __attribute__((ext_vector_type(4))) float f32x4;

static __device__ __forceinline__ unsigned short f2bf(float f) {
    __hip_bfloat16 h = __float2bfloat16(f);
    return *reinterpret_cast<unsigned short*>(&h);
}
static __device__ __forceinline__ float bf2f(unsigned short u) {
    __hip_bfloat16 h = *reinterpret_cast<__hip_bfloat16*>(&u);
    return __bfloat162float(h);
}

// ---------------- Kernel 0: pack adj into bitmask  padj[i][j/32] bit j%32
__global__ __launch_bounds__(256) void pack_adj_kernel(
    const int* __restrict__ adj, unsigned int* __restrict__ padj)
{
    const int gw   = (blockIdx.x * 256 + threadIdx.x) >> 6; // wave id
    const int lane = threadIdx.x & 63;
    const int i  = gw >> 5;            // 0..2047
    const int j0 = (gw & 31) * 64;     // 0..1984
    int ad = adj[(size_t)i * NN + j0 + lane];
    unsigned long long m = __ballot(ad > 0);
    if (lane == 0)  padj[i * 64 + (j0 >> 5)]     = (unsigned int)m;
    if (lane == 32) padj[i * 64 + (j0 >> 5) + 1] = (unsigned int)(m >> 32);
}

// ---------------- Kernel A: Wh = x @ W^T ; writes WhbT bf16 [b][d][n], f1, f2
__global__ __launch_bounds__(256) void wh_kernel(
    const float* __restrict__ x, const float* __restrict__ W,
    const float* __restrict__ a,
    __hip_bfloat16* __restrict__ WhbT,
    float* __restrict__ f1, float* __restrict__ f2)
{
    __shared__ float Wt[128 * 132];   // Wt[c][d] f32
    __shared__ float xs[32 * 128];    // x tile; reused as bf16 T[32][136] later
    __shared__ float sa[256];
    const int tid = threadIdx.x;
    const int b  = blockIdx.y;
    const int n0 = blockIdx.x * 32;

    sa[tid] = a[tid];
    #pragma unroll
    for (int k = 0; k < 16; ++k) {
        int g  = tid + 256 * k;
        int d  = g >> 5, c4 = g & 31;
        float4 wv = *(const float4*)&W[d * 128 + c4 * 4];
        Wt[(c4 * 4 + 0) * 132 + d] = wv.x;
        Wt[(c4 * 4 + 1) * 132 + d] = wv.y;
        Wt[(c4 * 4 + 2) * 132 + d] = wv.z;
        Wt[(c4 * 4 + 3) * 132 + d] = wv.w;
    }
    #pragma unroll
    for (int k = 0; k < 4; ++k) {
        int g = tid + 256 * k;
        int r = g >> 5, c4 = g & 31;
        *(float4*)&xs[r * 128 + c4 * 4] =
            *(const float4*)&x[(size_t)(b * NN + n0 + r) * CC + c4 * 4];
    }
    __syncthreads();

    const int rg   = tid >> 5;          // row group 0..7
    const int m    = tid & 31;
    const int dcol = m * 4;
    float4 acc[4];
    #pragma unroll
    for (int r = 0; r < 4; ++r) acc[r] = make_float4(0.f, 0.f, 0.f, 0.f);

    for (int c = 0; c < 128; ++c) {
        float4 wv = *(const float4*)&Wt[c * 132 + dcol];
        #pragma unroll
        for (int r = 0; r < 4; ++r) {
            float xr = xs[(rg * 4 + r) * 128 + c];
            acc[r].x += xr * wv.x; acc[r].y += xr * wv.y;
            acc[r].z += xr * wv.z; acc[r].w += xr * wv.w;
        }
    }

    // f1/f2 fused: reduce over the 32 lanes sharing a row group
    float p1[4], p2[4];
    #pragma unroll
    for (int r = 0; r < 4; ++r) {
        p1[r] = acc[r].x * sa[dcol] + acc[r].y * sa[dcol + 1] +
                acc[r].z * sa[dcol + 2] + acc[r].w * sa[dcol + 3];
        p2[r] = acc[r].x * sa[128 + dcol] + acc[r].y * sa[128 + dcol + 1] +
                acc[r].z * sa[128 + dcol + 2] + acc[r].w * sa[128 + dcol + 3];
    }
    #pragma unroll
    for (int off = 16; off > 0; off >>= 1) {
        #pragma unroll
        for (int r = 0; r < 4; ++r) {
            p1[r] += __shfl_xor(p1[r], off, 32);
            p2[r] += __shfl_xor(p2[r], off, 32);
        }
    }
    if (m == 0) {
        #pragma unroll
        for (int r = 0; r < 4; ++r) {
            f1[b * NN + n0 + rg * 4 + r] = p1[r];
            f2[b * NN + n0 + rg * 4 + r] = p2[r];
        }
    }

    // transpose bounce: bf16 T[32][136] in xs
    __syncthreads();
    unsigned short* T = reinterpret_cast<unsigned short*>(xs);
    #pragma unroll
    for (int r = 0; r < 4; ++r) {
        ushort4 tv;
        tv.x = f2bf(acc[r].x); tv.y = f2bf(acc[r].y);
        tv.z = f2bf(acc[r].z); tv.w = f2bf(acc[r].w);
        *(ushort4*)&T[(rg * 4 + r) * 136 + dcol] = tv;
    }
    __syncthreads();

    const int d = tid & 127;
    const int h = tid >> 7;       // 0..1 -> n-halves of 16
    unsigned int u[8];
    #pragma unroll
    for (int k = 0; k < 8; ++k) {
        unsigned short lo = T[(h * 16 + 2 * k)     * 136 + d];
        unsigned short hi = T[(h * 16 + 2 * k + 1) * 136 + d];
        u[k] = (unsigned int)lo | ((unsigned int)hi << 16);
    }
    __hip_bfloat16* dst = &WhbT[((size_t)(b * 128 + d)) * NN + n0 + h * 16];
    *(uint4*)dst       = make_uint4(u[0], u[1], u[2], u[3]);
    *(uint4*)(dst + 8) = make_uint4(u[4], u[5], u[6], u[7]);
}

// ---------------- Kernel C: MFMA attention. Block: 32 i-rows x 128 d, 1 batch.
__global__ __launch_bounds__(256) void gat_kernel(
    const __hip_bfloat16* __restrict__ WhbT,   // [b][128 d][2048 n]
    const unsigned int* __restrict__ padj,     // [2048][64]
    const float* __restrict__ f1, const float* __restrict__ f2,
    float* __restrict__ out)
{
    // XOR-swizzled bf16 tiles: elem (row, j) -> row*64 + ((j/8 ^ (row&7))*8) + j%8
    __shared__ __align__(16) unsigned short Bs[128 * 64];  // WhbT chunk [d][64 j]
    __shared__ __align__(16) unsigned short Ps[32 * 64];   // P chunk    [i][64 j]
    __shared__ float f2s[NN];
    __shared__ float Sp[4][32];
    __shared__ float Sinv[32];

    const int tid = threadIdx.x;
    const int b   = blockIdx.y;
    const int i0  = blockIdx.x * 32;

    #pragma unroll
    for (int k = 0; k < 8; ++k) f2s[tid + 256 * k] = f2[b * NN + tid + 256 * k];

    // P-compute role
    const int prow = tid & 31;
    const int pjb  = tid >> 5;                 // 0..7
    const float f1r = f1[b * NN + i0 + prow];
    const unsigned int* padjRow = padj + (size_t)(i0 + prow) * 64;
    const int psw = ((pjb ^ (prow & 7)) << 3); // swizzled block offset
    float s_part = 0.f;

    // MFMA role
    const int w    = tid >> 6;
    const int lane = tid & 63;
    const int fr   = lane & 15;
    const int fk   = lane >> 4;                // 0..3
    f32x4 acc00 = {0.f,0.f,0.f,0.f}, acc01 = {0.f,0.f,0.f,0.f};
    f32x4 acc10 = {0.f,0.f,0.f,0.f}, acc11 = {0.f,0.f,0.f,0.f};

    const size_t wbase = (size_t)b * 128 * NN;
    __syncthreads();

    for (int jc = 0; jc < 32; ++jc) {
        const int j0 = jc * 64;
        // (A) issue global loads for B-stage
        uint4 br0, br1, br2, br3;
        {
            int g0 = tid;           // d = g>>3, jb = g&7
            br0 = *(const uint4*)&WhbT[wbase + (size_t)(g0 >> 3) * NN + j0 + (g0 & 7) * 8];
            int g1 = 256 + tid;
            br1 = *(const uint4*)&WhbT[wbase + (size_t)(g1 >> 3) * NN + j0 + (g1 & 7) * 8];
            int g2 = 512 + tid;
            br2 = *(const uint4*)&WhbT[wbase + (size_t)(g2 >> 3) * NN + j0 + (g2 & 7) * 8];
            int g3 = 768 + tid;
            br3 = *(const uint4*)&WhbT[wbase + (size_t)(g3 >> 3) * NN + j0 + (g3 & 7) * 8];
        }
        // (B) compute P chunk (row prow, j = j0 + pjb*8 + e)
        unsigned int pw = padjRow[(j0 >> 5) + (pjb >> 2)];
        unsigned int pbyte = (pw >> ((pjb & 3) * 8)) & 0xffu;
        unsigned short pks[8];
        float ssum = 0.f;
        #pragma unroll
        for (int e = 0; e < 8; ++e) {
            float ev = f1r + f2s[j0 + pjb * 8 + e];
            ev = (ev > 0.f) ? ev : 0.2f * ev;
            float wv = ((pbyte >> e) & 1u) ? __expf(ev) : 0.f;
            unsigned short bw = f2bf(wv);
            pks[e] = bw;
            ssum += bf2f(bw);       // sum the ROUNDED value (consistency)
        }
        s_part += ssum;

        __syncthreads();   // previous MFMA phase done reading LDS
        // (C) LDS writes, swizzled
        {
            int g0 = tid;
            *(uint4*)&Bs[(g0 >> 3) * 64 + ((((g0 & 7)) ^ ((g0 >> 3) & 7)) << 3)] = br0;
            int g1 = 256 + tid;
            *(uint4*)&Bs[(g1 >> 3) * 64 + ((((g1 & 7)) ^ ((g1 >> 3) & 7)) << 3)] = br1;
            int g2 = 512 + tid;
            *(uint4*)&Bs[(g2 >> 3) * 64 + ((((g2 & 7)) ^ ((g2 >> 3) & 7)) << 3)] = br2;
            int g3 = 768 + tid;
            *(uint4*)&Bs[(g3 >> 3) * 64 + ((((g3 & 7)) ^ ((g3 >> 3) & 7)) << 3)] = br3;
            uint4 pv;
            pv.x = (unsigned int)pks[0] | ((unsigned int)pks[1] << 16);
            pv.y = (unsigned int)pks[2] | ((unsigned int)pks[3] << 16);
            pv.z = (unsigned int)pks[4] | ((unsigned int)pks[5] << 16);
            pv.w = (unsigned int)pks[6] | ((unsigned int)pks[7] << 16);
            *(uint4*)&Ps[prow * 64 + psw] = pv;
        }
        __syncthreads();   // tiles ready
        // (D) MFMA: wave w covers d-cols w*32 .. w*32+31, i-rows 0..31
        #pragma unroll
        for (int ks = 0; ks < 2; ++ks) {
            const int jbl = ks * 4 + fk;
            const int sb  = ((jbl ^ (fr & 7)) << 3);
            short8 aF0 = *(const short8*)&Ps[fr * 64 + sb];
            short8 aF1 = *(const short8*)&Ps[(16 + fr) * 64 + sb];
            short8 bF0 = *(const short8*)&Bs[(w * 32 + fr) * 64 + sb];
            short8 bF1 = *(const short8*)&Bs[(w * 32 + 16 + fr) * 64 + sb];
            acc00 = __builtin_amdgcn_mfma_f32_16x16x32_bf16(aF0, bF0, acc00, 0, 0, 0);
            acc01 = __builtin_amdgcn_mfma_f32_16x16x32_bf16(aF0, bF1, acc01, 0, 0, 0);
            acc10 = __builtin_amdgcn_mfma_f32_16x16x32_bf16(aF1, bF0, acc10, 0, 0, 0);
            acc11 = __builtin_amdgcn_mfma_f32_16x16x32_bf16(aF1, bF1, acc11, 0, 0, 0);
        }
    }

    // row-sum reduce: pair (lane, lane+32) then cross-wave via LDS
    float v2 = s_part + __shfl_xor(s_part, 32);
    if (lane < 32) Sp[w][lane] = v2;
    __syncthreads();
    if (tid < 32) Sinv[tid] = 1.0f / (Sp[0][tid] + Sp[1][tid] + Sp[2][tid] + Sp[3][tid]);
    __syncthreads();

    // epilogue: C/D layout col = lane&15, row = fk*4 + reg
    #pragma unroll
    for (int it = 0; it < 2; ++it) {
        #pragma unroll
        for (int dt = 0; dt < 2; ++dt) {
            f32x4 av = (it == 0) ? (dt == 0 ? acc00 : acc01)
                                 : (dt == 0 ? acc10 : acc11);
            #pragma unroll
            for (int r = 0; r < 4; ++r) {
                int i = it * 16 + fk * 4 + r;
                int d = w * 32 + dt * 16 + fr;
                float hv = av[r] * Sinv[i];
                hv = (hv > 0.f) ? hv : expm1f(hv);
                out[((size_t)(b * NN) + i0 + i) * DD + d] = hv;
            }
        }
    }
}

extern "C" void kernel_launch(void* const* d_in, const int* in_sizes, int n_in,
                              void* d_out, int out_size, void* d_ws, size_t ws_size,
                              hipStream_t stream) {
    const float* x   = (const float*)d_in[0];
    const int*   adj = (const int*)d_in[1];
    const float* W   = (const float*)d_in[2];
    const float* a   = (const float*)d_in[3];
    float* out = (float*)d_out;

    __hip_bfloat16* WhbT = (__hip_bfloat16*)d_ws;              // 4 MB
    float* f1 = (float*)((char*)d_ws + (4u << 20));            // 64 KB
    float* f2 = f1 + BB * NN;                                  // 64 KB
    unsigned int* padj = (unsigned int*)(f2 + BB * NN);        // 512 KB

    pack_adj_kernel<<<NN * NN / 64 / 4, 256, 0, stream>>>(adj, padj);
    wh_kernel<<<dim3(NN / 32, BB), 256, 0, stream>>>(x, W, a, WhbT, f1, f2);
    gat_kernel<<<dim3(NN / 32, BB), 256, 0, stream>>>(WhbT, padj, f1, f2, out);
}

// Round 3
// 73.278 us; speedup vs baseline: 2.8899x; 1.0637x over previous
//
#include <hip/hip_runtime.h>
#include <hip/hip_bf16.h>
#include <math.h>

#define BB 8
#define NN 2048
#define CC 128
#define DD 128

typedef __attribute__((ext_vector_type(8))) short short8;
typedef __attribute__((ext_vector_type(4))) float f32x4;

static __device__ __forceinline__ unsigned short f2bf(float f) {
    __hip_bfloat16 h = __float2bfloat16(f);
    return *reinterpret_cast<unsigned short*>(&h);
}
static __device__ __forceinline__ float bf2f(unsigned short u) {
    __hip_bfloat16 h = *reinterpret_cast<__hip_bfloat16*>(&u);
    return __bfloat162float(h);
}

// ---------------- Kernel 0: pack adj into bitmask  padj[i][j/32] bit j%32
__global__ __launch_bounds__(256) void pack_adj_kernel(
    const int* __restrict__ adj, unsigned int* __restrict__ padj)
{
    const int gw   = (blockIdx.x * 256 + threadIdx.x) >> 6;
    const int lane = threadIdx.x & 63;
    const int i  = gw >> 5;
    const int j0 = (gw & 31) * 64;
    int ad = adj[(size_t)i * NN + j0 + lane];
    unsigned long long m = __ballot(ad > 0);
    if (lane == 0)  padj[i * 64 + (j0 >> 5)]     = (unsigned int)m;
    if (lane == 32) padj[i * 64 + (j0 >> 5) + 1] = (unsigned int)(m >> 32);
}

// ---------------- Kernel A: Wh = x @ W^T ; writes WhbT bf16 [b][d][n], f1, f2
__global__ __launch_bounds__(256) void wh_kernel(
    const float* __restrict__ x, const float* __restrict__ W,
    const float* __restrict__ a,
    __hip_bfloat16* __restrict__ WhbT,
    float* __restrict__ f1, float* __restrict__ f2)
{
    __shared__ float Wt[128 * 132];
    __shared__ float xs[32 * 128];
    __shared__ float sa[256];
    const int tid = threadIdx.x;
    const int b  = blockIdx.y;
    const int n0 = blockIdx.x * 32;

    sa[tid] = a[tid];
    #pragma unroll
    for (int k = 0; k < 16; ++k) {
        int g  = tid + 256 * k;
        int d  = g >> 5, c4 = g & 31;
        float4 wv = *(const float4*)&W[d * 128 + c4 * 4];
        Wt[(c4 * 4 + 0) * 132 + d] = wv.x;
        Wt[(c4 * 4 + 1) * 132 + d] = wv.y;
        Wt[(c4 * 4 + 2) * 132 + d] = wv.z;
        Wt[(c4 * 4 + 3) * 132 + d] = wv.w;
    }
    #pragma unroll
    for (int k = 0; k < 4; ++k) {
        int g = tid + 256 * k;
        int r = g >> 5, c4 = g & 31;
        *(float4*)&xs[r * 128 + c4 * 4] =
            *(const float4*)&x[(size_t)(b * NN + n0 + r) * CC + c4 * 4];
    }
    __syncthreads();

    const int rg   = tid >> 5;
    const int m    = tid & 31;
    const int dcol = m * 4;
    float4 acc[4];
    #pragma unroll
    for (int r = 0; r < 4; ++r) acc[r] = make_float4(0.f, 0.f, 0.f, 0.f);

    for (int c = 0; c < 128; ++c) {
        float4 wv = *(const float4*)&Wt[c * 132 + dcol];
        #pragma unroll
        for (int r = 0; r < 4; ++r) {
            float xr = xs[(rg * 4 + r) * 128 + c];
            acc[r].x += xr * wv.x; acc[r].y += xr * wv.y;
            acc[r].z += xr * wv.z; acc[r].w += xr * wv.w;
        }
    }

    float p1[4], p2[4];
    #pragma unroll
    for (int r = 0; r < 4; ++r) {
        p1[r] = acc[r].x * sa[dcol] + acc[r].y * sa[dcol + 1] +
                acc[r].z * sa[dcol + 2] + acc[r].w * sa[dcol + 3];
        p2[r] = acc[r].x * sa[128 + dcol] + acc[r].y * sa[128 + dcol + 1] +
                acc[r].z * sa[128 + dcol + 2] + acc[r].w * sa[128 + dcol + 3];
    }
    #pragma unroll
    for (int off = 16; off > 0; off >>= 1) {
        #pragma unroll
        for (int r = 0; r < 4; ++r) {
            p1[r] += __shfl_xor(p1[r], off, 32);
            p2[r] += __shfl_xor(p2[r], off, 32);
        }
    }
    if (m == 0) {
        #pragma unroll
        for (int r = 0; r < 4; ++r) {
            f1[b * NN + n0 + rg * 4 + r] = p1[r];
            f2[b * NN + n0 + rg * 4 + r] = p2[r];
        }
    }

    __syncthreads();
    unsigned short* T = reinterpret_cast<unsigned short*>(xs);
    #pragma unroll
    for (int r = 0; r < 4; ++r) {
        ushort4 tv;
        tv.x = f2bf(acc[r].x); tv.y = f2bf(acc[r].y);
        tv.z = f2bf(acc[r].z); tv.w = f2bf(acc[r].w);
        *(ushort4*)&T[(rg * 4 + r) * 136 + dcol] = tv;
    }
    __syncthreads();

    const int d = tid & 127;
    const int h = tid >> 7;
    unsigned int u[8];
    #pragma unroll
    for (int k = 0; k < 8; ++k) {
        unsigned short lo = T[(h * 16 + 2 * k)     * 136 + d];
        unsigned short hi = T[(h * 16 + 2 * k + 1) * 136 + d];
        u[k] = (unsigned int)lo | ((unsigned int)hi << 16);
    }
    __hip_bfloat16* dst = &WhbT[((size_t)(b * 128 + d)) * NN + n0 + h * 16];
    *(uint4*)dst       = make_uint4(u[0], u[1], u[2], u[3]);
    *(uint4*)(dst + 8) = make_uint4(u[4], u[5], u[6], u[7]);
}

// ---------------- Kernel C: MFMA attention over a j-split.
// Block: 32 i-rows x 128 d, one (batch, split). S splits of the j axis;
// partial PV / S written to workspace (or final out when DIRECT).
template<int S, bool DIRECT>
__global__ __launch_bounds__(256) void gat_kernel(
    const __hip_bfloat16* __restrict__ WhbT,   // [b][128 d][2048 n]
    const unsigned int* __restrict__ padj,     // [2048][64]
    const float* __restrict__ f1, const float* __restrict__ f2,
    float* __restrict__ out,
    float* __restrict__ pPV, float* __restrict__ pS)
{
    constexpr int JS = NN / S;     // j extent per split
    constexpr int NC = JS / 64;    // 64-j chunks
    __shared__ __align__(16) unsigned short Bs[128 * 64];
    __shared__ __align__(16) unsigned short Ps[32 * 64];
    __shared__ float f2s[JS];
    __shared__ float Sp[4][32];
    __shared__ float Sred[32];

    const int tid   = threadIdx.x;
    const int i0    = blockIdx.x * 32;
    const int split = blockIdx.y;
    const int b     = blockIdx.z;
    const int jBeg  = split * JS;

    #pragma unroll
    for (int k = 0; k < JS / 256; ++k)
        f2s[tid + 256 * k] = f2[b * NN + jBeg + tid + 256 * k];

    // P-compute role
    const int prow = tid & 31;
    const int pjb  = tid >> 5;
    const float f1r = f1[b * NN + i0 + prow];
    const unsigned int* padjRow = padj + (size_t)(i0 + prow) * 64;
    const int psw = ((pjb ^ (prow & 7)) << 3);

    // MFMA role
    const int w    = tid >> 6;
    const int lane = tid & 63;
    const int fr   = lane & 15;
    const int fk   = lane >> 4;
    f32x4 acc00 = {0.f,0.f,0.f,0.f}, acc01 = {0.f,0.f,0.f,0.f};
    f32x4 acc10 = {0.f,0.f,0.f,0.f}, acc11 = {0.f,0.f,0.f,0.f};
    float s_part = 0.f;

    const size_t wbase = (size_t)b * 128 * NN;
    const int gd0 = tid >> 3,        gj0 = (tid & 7) * 8;
    const int gd1 = (256 + tid) >> 3, gj1 = ((256 + tid) & 7) * 8;
    const int gd2 = (512 + tid) >> 3, gj2 = ((512 + tid) & 7) * 8;
    const int gd3 = (768 + tid) >> 3, gj3 = ((768 + tid) & 7) * 8;
    // swizzled LDS write offsets (fixed per thread)
    const int sw0 = gd0 * 64 + ((((tid & 7))        ^ (gd0 & 7)) << 3);
    const int sw1 = gd1 * 64 + (((((256+tid) & 7))  ^ (gd1 & 7)) << 3);
    const int sw2 = gd2 * 64 + (((((512+tid) & 7))  ^ (gd2 & 7)) << 3);
    const int sw3 = gd3 * 64 + (((((768+tid) & 7))  ^ (gd3 & 7)) << 3);

    // prefetch chunk 0
    uint4 br0 = *(const uint4*)&WhbT[wbase + (size_t)gd0 * NN + jBeg + gj0];
    uint4 br1 = *(const uint4*)&WhbT[wbase + (size_t)gd1 * NN + jBeg + gj1];
    uint4 br2 = *(const uint4*)&WhbT[wbase + (size_t)gd2 * NN + jBeg + gj2];
    uint4 br3 = *(const uint4*)&WhbT[wbase + (size_t)gd3 * NN + jBeg + gj3];
    unsigned int pw = padjRow[(jBeg >> 5) + (pjb >> 2)];

    __syncthreads();   // f2s ready

    for (int c = 0; c < NC; ++c) {
        // (B) compute P chunk
        unsigned int pbyte = (pw >> ((pjb & 3) * 8)) & 0xffu;
        unsigned short pks[8];
        float ssum = 0.f;
        #pragma unroll
        for (int e = 0; e < 8; ++e) {
            float ev = f1r + f2s[c * 64 + pjb * 8 + e];
            ev = (ev > 0.f) ? ev : 0.2f * ev;
            float wv = ((pbyte >> e) & 1u) ? __expf(ev) : 0.f;
            unsigned short bw = f2bf(wv);
            pks[e] = bw;
            ssum += bf2f(bw);
        }
        s_part += ssum;

        if (c > 0) __syncthreads();   // prev MFMA done reading LDS
        // (C) LDS writes from prefetched regs
        *(uint4*)&Bs[sw0] = br0;
        *(uint4*)&Bs[sw1] = br1;
        *(uint4*)&Bs[sw2] = br2;
        *(uint4*)&Bs[sw3] = br3;
        {
            uint4 pv;
            pv.x = (unsigned int)pks[0] | ((unsigned int)pks[1] << 16);
            pv.y = (unsigned int)pks[2] | ((unsigned int)pks[3] << 16);
            pv.z = (unsigned int)pks[4] | ((unsigned int)pks[5] << 16);
            pv.w = (unsigned int)pks[6] | ((unsigned int)pks[7] << 16);
            *(uint4*)&Ps[prow * 64 + psw] = pv;
        }
        // (A) prefetch chunk c+1 (hides L2 latency under barrier+MFMA)
        if (c + 1 < NC) {
            const int j0n = jBeg + (c + 1) * 64;
            br0 = *(const uint4*)&WhbT[wbase + (size_t)gd0 * NN + j0n + gj0];
            br1 = *(const uint4*)&WhbT[wbase + (size_t)gd1 * NN + j0n + gj1];
            br2 = *(const uint4*)&WhbT[wbase + (size_t)gd2 * NN + j0n + gj2];
            br3 = *(const uint4*)&WhbT[wbase + (size_t)gd3 * NN + j0n + gj3];
            pw  = padjRow[(j0n >> 5) + (pjb >> 2)];
        }
        __syncthreads();   // tiles ready
        // (D) MFMA
        #pragma unroll
        for (int ks = 0; ks < 2; ++ks) {
            const int jbl = ks * 4 + fk;
            const int sb  = ((jbl ^ (fr & 7)) << 3);
            short8 aF0 = *(const short8*)&Ps[fr * 64 + sb];
            short8 aF1 = *(const short8*)&Ps[(16 + fr) * 64 + sb];
            short8 bF0 = *(const short8*)&Bs[(w * 32 + fr) * 64 + sb];
            short8 bF1 = *(const short8*)&Bs[(w * 32 + 16 + fr) * 64 + sb];
            acc00 = __builtin_amdgcn_mfma_f32_16x16x32_bf16(aF0, bF0, acc00, 0, 0, 0);
            acc01 = __builtin_amdgcn_mfma_f32_16x16x32_bf16(aF0, bF1, acc01, 0, 0, 0);
            acc10 = __builtin_amdgcn_mfma_f32_16x16x32_bf16(aF1, bF0, acc10, 0, 0, 0);
            acc11 = __builtin_amdgcn_mfma_f32_16x16x32_bf16(aF1, bF1, acc11, 0, 0, 0);
        }
    }

    // row-sum reduce
    float v2 = s_part + __shfl_xor(s_part, 32);
    if (lane < 32) Sp[w][lane] = v2;
    __syncthreads();
    if (tid < 32) {
        float st = Sp[0][tid] + Sp[1][tid] + Sp[2][tid] + Sp[3][tid];
        if (DIRECT) {
            Sred[tid] = 1.0f / st;
        } else {
            pS[(size_t)(b * S + split) * NN + i0 + tid] = st;
        }
    }
    __syncthreads();

    #pragma unroll
    for (int it = 0; it < 2; ++it) {
        #pragma unroll
        for (int dt = 0; dt < 2; ++dt) {
            f32x4 av = (it == 0) ? (dt == 0 ? acc00 : acc01)
                                 : (dt == 0 ? acc10 : acc11);
            #pragma unroll
            for (int r = 0; r < 4; ++r) {
                int i = it * 16 + fk * 4 + r;
                int d = w * 32 + dt * 16 + fr;
                if (DIRECT) {
                    float hv = av[r] * Sred[i];
                    hv = (hv > 0.f) ? hv : expm1f(hv);
                    out[((size_t)(b * NN) + i0 + i) * DD + d] = hv;
                } else {
                    pPV[((size_t)(b * S + split) * NN + i0 + i) * DD + d] = av[r];
                }
            }
        }
    }
}

// ---------------- Kernel D: combine splits, normalize, elu
template<int S>
__global__ __launch_bounds__(256) void reduce_kernel(
    const float* __restrict__ pPV, const float* __restrict__ pS,
    float* __restrict__ out)
{
    const int idx = blockIdx.x * 256 + threadIdx.x;   // (b,i,d4)
    const int bi = idx >> 5;
    const int d4 = (idx & 31) * 4;
    const int b  = bi >> 11;
    const int i  = bi & 2047;
    float4 sum = make_float4(0.f, 0.f, 0.f, 0.f);
    float ssum = 0.f;
    #pragma unroll
    for (int s = 0; s < S; ++s) {
        size_t base = (size_t)(b * S + s) * NN + i;
        float4 v = *(const float4*)&pPV[base * DD + d4];
        sum.x += v.x; sum.y += v.y; sum.z += v.z; sum.w += v.w;
        ssum  += pS[base];
    }
    float inv = 1.0f / ssum;
    float4 h;
    h.x = sum.x * inv; h.y = sum.y * inv; h.z = sum.z * inv; h.w = sum.w * inv;
    h.x = (h.x > 0.f) ? h.x : expm1f(h.x);
    h.y = (h.y > 0.f) ? h.y : expm1f(h.y);
    h.z = (h.z > 0.f) ? h.z : expm1f(h.z);
    h.w = (h.w > 0.f) ? h.w : expm1f(h.w);
    *(float4*)&out[(size_t)bi * DD + d4] = h;
}

extern "C" void kernel_launch(void* const* d_in, const int* in_sizes, int n_in,
                              void* d_out, int out_size, void* d_ws, size_t ws_size,
                              hipStream_t stream) {
    const float* x   = (const float*)d_in[0];
    const int*   adj = (const int*)d_in[1];
    const float* W   = (const float*)d_in[2];
    const float* a   = (const float*)d_in[3];
    float* out = (float*)d_out;

    __hip_bfloat16* WhbT = (__hip_bfloat16*)d_ws;              // 4 MB
    float* f1 = (float*)((char*)d_ws + (4u << 20));            // 64 KB
    float* f2 = f1 + BB * NN;                                  // 64 KB
    unsigned int* padj = (unsigned int*)(f2 + BB * NN);        // 512 KB
    float* pPV = (float*)((char*)d_ws + (4u << 20) + 2 * BB * NN * 4 + NN * 64 * 4);

    const size_t base_bytes = (4u << 20) + (size_t)2 * BB * NN * 4 + (size_t)NN * 64 * 4;
    const size_t per_split  = (size_t)BB * NN * DD * 4 + (size_t)BB * NN * 4;

    pack_adj_kernel<<<NN * NN / 64 / 4, 256, 0, stream>>>(adj, padj);
    wh_kernel<<<dim3(NN / 32, BB), 256, 0, stream>>>(x, W, a, WhbT, f1, f2);

    if (ws_size >= base_bytes + 4 * per_split) {
        constexpr int S = 4;
        float* pS = pPV + (size_t)S * BB * NN * DD;
        gat_kernel<S, false><<<dim3(NN / 32, S, BB), 256, 0, stream>>>(
            WhbT, padj, f1, f2, out, pPV, pS);
        reduce_kernel<S><<<BB * NN * DD / 4 / 256, 256, 0, stream>>>(pPV, pS, out);
    } else if (ws_size >= base_bytes + 2 * per_split) {
        constexpr int S = 2;
        float* pS = pPV + (size_t)S * BB * NN * DD;
        gat_kernel<S, false><<<dim3(NN / 32, S, BB), 256, 0, stream>>>(
            WhbT, padj, f1, f2, out, pPV, pS);
        reduce_kernel<S><<<BB * NN * DD / 4 / 256, 256, 0, stream>>>(pPV, pS, out);
    } else {
        gat_kernel<1, true><<<dim3(NN / 32, 1, BB), 256, 0, stream>>>(
            WhbT, padj, f1, f2, out, nullptr, nullptr);
    }
}

// Round 4
// 58.998 us; speedup vs baseline: 3.5894x; 1.2420x over previous
//
#include <hip/hip_runtime.h>
#include <hip/hip_bf16.h>
#include <math.h>

#define BB 8
#define NN 2048
#define CC 128
#define DD 128

typedef __attribute__((ext_vector_type(8))) short short8;
typedef __attribute__((ext_vector_type(4))) float f32x4;

static __device__ __forceinline__ unsigned short f2bf(float f) {
    __hip_bfloat16 h = __float2bfloat16(f);
    return *reinterpret_cast<unsigned short*>(&h);
}
static __device__ __forceinline__ float bf2f(unsigned short u) {
    __hip_bfloat16 h = *reinterpret_cast<__hip_bfloat16*>(&u);
    return __bfloat162float(h);
}

// ---------------- Kernel 0: split W into bf16 hi/lo (error-compensated MFMA inputs)
__global__ __launch_bounds__(256) void wsplit_kernel(
    const float* __restrict__ W,
    unsigned short* __restrict__ Whi, unsigned short* __restrict__ Wlo)
{
    int g = blockIdx.x * 256 + threadIdx.x;   // 16384 elems
    float w = W[g];
    unsigned short h = f2bf(w);
    Whi[g] = h;
    Wlo[g] = f2bf(w - bf2f(h));
}

// ---------------- Kernel A: Wh = x @ W^T via MFMA (hi/lo compensated, f32-accurate)
// Writes WhbT bf16 [b][d][n], f1, f2. Block: 64 n-rows, 4 waves x 16 rows. No LDS.
__global__ __launch_bounds__(256) void wh_kernel(
    const float* __restrict__ x,
    const unsigned short* __restrict__ Whi, const unsigned short* __restrict__ Wlo,
    const float* __restrict__ a,
    unsigned short* __restrict__ WhbT,
    float* __restrict__ f1, float* __restrict__ f2)
{
    const int tid  = threadIdx.x;
    const int b    = blockIdx.y;
    const int n0   = blockIdx.x * 64;
    const int w    = tid >> 6;
    const int lane = tid & 63;
    const int fr   = lane & 15, fk = lane >> 4;
    const int n    = n0 + w * 16 + fr;          // this lane's x row (B operand)

    // Build B-fragments (x row) as bf16 hi/lo in registers.
    short8 bh[4], bl[4];
    const float* xrow = &x[((size_t)(b * NN) + n) * CC];
    #pragma unroll
    for (int ks = 0; ks < 4; ++ks) {
        float xv[8];
        *(float4*)&xv[0] = *(const float4*)&xrow[(ks * 4 + fk) * 8];
        *(float4*)&xv[4] = *(const float4*)&xrow[(ks * 4 + fk) * 8 + 4];
        #pragma unroll
        for (int e = 0; e < 8; ++e) {
            unsigned short h = f2bf(xv[e]);
            bh[ks][e] = (short)h;
            bl[ks][e] = (short)f2bf(xv[e] - bf2f(h));
        }
    }

    f32x4 acc[8];
    #pragma unroll
    for (int dt = 0; dt < 8; ++dt) acc[dt] = (f32x4){0.f, 0.f, 0.f, 0.f};

    // A = W rows (d), read hi/lo frags from global (L2-hot, 64 KB).
    #pragma unroll
    for (int dt = 0; dt < 8; ++dt) {
        #pragma unroll
        for (int ks = 0; ks < 4; ++ks) {
            const int off = (dt * 16 + fr) * CC + (ks * 4 + fk) * 8;
            short8 aH = *(const short8*)&Whi[off];
            short8 aL = *(const short8*)&Wlo[off];
            acc[dt] = __builtin_amdgcn_mfma_f32_16x16x32_bf16(aH, bh[ks], acc[dt], 0, 0, 0);
            acc[dt] = __builtin_amdgcn_mfma_f32_16x16x32_bf16(aH, bl[ks], acc[dt], 0, 0, 0);
            acc[dt] = __builtin_amdgcn_mfma_f32_16x16x32_bf16(aL, bh[ks], acc[dt], 0, 0, 0);
        }
    }
    // acc[dt][r]: Wh[d = dt*16 + fk*4 + r][n]  (C row = A row = d, C col = B row = n)

    // f1/f2: dot over d (in-lane over dt,r; cross-lane over fk groups)
    float p1 = 0.f, p2 = 0.f;
    #pragma unroll
    for (int dt = 0; dt < 8; ++dt) {
        #pragma unroll
        for (int r = 0; r < 4; ++r) {
            const int d = dt * 16 + fk * 4 + r;
            p1 += acc[dt][r] * a[d];
            p2 += acc[dt][r] * a[DD + d];
        }
    }
    p1 += __shfl_xor(p1, 16); p1 += __shfl_xor(p1, 32);
    p2 += __shfl_xor(p2, 16); p2 += __shfl_xor(p2, 32);
    if (fk == 0) {
        f1[b * NN + n] = p1;
        f2[b * NN + n] = p2;
    }

    // WhbT[d][n] bf16 stores (16-lane groups are 32B-contiguous in n)
    #pragma unroll
    for (int dt = 0; dt < 8; ++dt) {
        #pragma unroll
        for (int r = 0; r < 4; ++r) {
            const int d = dt * 16 + fk * 4 + r;
            WhbT[((size_t)(b * 128 + d)) * NN + n] = f2bf(acc[dt][r]);
        }
    }
}

// ---------------- Kernel C: MFMA attention over a j-split, adj fused, reg-prefetched.
template<int S, bool DIRECT>
__global__ __launch_bounds__(256) void gat_kernel(
    const unsigned short* __restrict__ WhbT,   // [b][128 d][2048 n] bf16
    const int* __restrict__ adj,
    const float* __restrict__ f1, const float* __restrict__ f2,
    float* __restrict__ out,
    float* __restrict__ pPV, float* __restrict__ pS)
{
    constexpr int JS = NN / S;
    constexpr int NC = JS / 64;
    __shared__ __align__(16) unsigned short Bs[128 * 64];  // 16 KB
    __shared__ __align__(16) unsigned short Ps[32 * 64];   // 4 KB
    __shared__ float Srow[32];
    __shared__ float Sred[32];

    const int tid   = threadIdx.x;
    const int i0    = blockIdx.x * 32;
    const int split = blockIdx.y;
    const int b     = blockIdx.z;
    const int jBeg  = split * JS;

    // P role: row = tid>>3 (coalesced adj), 8 j-elems at pjb*8
    const int prow = tid >> 3;
    const int pjb  = tid & 7;
    const float f1r = f1[b * NN + i0 + prow];
    const int psw = ((pjb ^ (prow & 7)) << 3);
    const int*   adjP = adj + (size_t)(i0 + prow) * NN + jBeg + pjb * 8;
    const float* f2P  = f2 + b * NN + jBeg + pjb * 8;

    // MFMA role
    const int w    = tid >> 6;
    const int lane = tid & 63;
    const int fr   = lane & 15;
    const int fk   = lane >> 4;
    f32x4 acc00 = {0.f,0.f,0.f,0.f}, acc01 = {0.f,0.f,0.f,0.f};
    f32x4 acc10 = {0.f,0.f,0.f,0.f}, acc11 = {0.f,0.f,0.f,0.f};
    float s_part = 0.f;

    // B staging thread map (16B per load, swizzled LDS slots)
    const size_t wbase = (size_t)b * 128 * NN;
    const int gd0 = tid >> 3,         gj0 = (tid & 7) * 8;
    const int gd1 = (256 + tid) >> 3, gj1 = ((256 + tid) & 7) * 8;
    const int gd2 = (512 + tid) >> 3, gj2 = ((512 + tid) & 7) * 8;
    const int gd3 = (768 + tid) >> 3, gj3 = ((768 + tid) & 7) * 8;
    const int sw0 = gd0 * 64 + ((((tid) & 7)       ^ (gd0 & 7)) << 3);
    const int sw1 = gd1 * 64 + ((((256 + tid) & 7) ^ (gd1 & 7)) << 3);
    const int sw2 = gd2 * 64 + ((((512 + tid) & 7) ^ (gd2 & 7)) << 3);
    const int sw3 = gd3 * 64 + ((((768 + tid) & 7) ^ (gd3 & 7)) << 3);

    // prefetch chunk 0
    uint4 br0 = *(const uint4*)&WhbT[wbase + (size_t)gd0 * NN + jBeg + gj0];
    uint4 br1 = *(const uint4*)&WhbT[wbase + (size_t)gd1 * NN + jBeg + gj1];
    uint4 br2 = *(const uint4*)&WhbT[wbase + (size_t)gd2 * NN + jBeg + gj2];
    uint4 br3 = *(const uint4*)&WhbT[wbase + (size_t)gd3 * NN + jBeg + gj3];
    int4   ad0 = *(const int4*)(adjP);
    int4   ad1 = *(const int4*)(adjP + 4);
    float4 fA  = *(const float4*)(f2P);
    float4 fB  = *(const float4*)(f2P + 4);

    for (int c = 0; c < NC; ++c) {
        // (B) compute P chunk from registers
        float fv[8]; int av[8];
        *(float4*)&fv[0] = fA; *(float4*)&fv[4] = fB;
        *(int4*)&av[0]   = ad0; *(int4*)&av[4]  = ad1;
        unsigned short pks[8];
        float ssum = 0.f;
        #pragma unroll
        for (int e = 0; e < 8; ++e) {
            float ev = f1r + fv[e];
            ev = (ev > 0.f) ? ev : 0.2f * ev;
            float wv = (av[e] > 0) ? __expf(ev) : 0.f;
            unsigned short bw = f2bf(wv);
            pks[e] = bw;
            ssum += bf2f(bw);     // sum the rounded value (num/denom consistency)
        }
        s_part += ssum;

        if (c > 0) __syncthreads();   // prev MFMA done reading LDS
        // (C) LDS writes from prefetched regs
        *(uint4*)&Bs[sw0] = br0;
        *(uint4*)&Bs[sw1] = br1;
        *(uint4*)&Bs[sw2] = br2;
        *(uint4*)&Bs[sw3] = br3;
        {
            uint4 pv;
            pv.x = (unsigned int)pks[0] | ((unsigned int)pks[1] << 16);
            pv.y = (unsigned int)pks[2] | ((unsigned int)pks[3] << 16);
            pv.z = (unsigned int)pks[4] | ((unsigned int)pks[5] << 16);
            pv.w = (unsigned int)pks[6] | ((unsigned int)pks[7] << 16);
            *(uint4*)&Ps[prow * 64 + psw] = pv;
        }
        // (A) prefetch chunk c+1
        if (c + 1 < NC) {
            const int j0n = jBeg + (c + 1) * 64;
            br0 = *(const uint4*)&WhbT[wbase + (size_t)gd0 * NN + j0n + gj0];
            br1 = *(const uint4*)&WhbT[wbase + (size_t)gd1 * NN + j0n + gj1];
            br2 = *(const uint4*)&WhbT[wbase + (size_t)gd2 * NN + j0n + gj2];
            br3 = *(const uint4*)&WhbT[wbase + (size_t)gd3 * NN + j0n + gj3];
            ad0 = *(const int4*)(adjP + (c + 1) * 64);
            ad1 = *(const int4*)(adjP + (c + 1) * 64 + 4);
            fA  = *(const float4*)(f2P + (c + 1) * 64);
            fB  = *(const float4*)(f2P + (c + 1) * 64 + 4);
        }
        __syncthreads();   // tiles ready
        // (D) MFMA
        __builtin_amdgcn_s_setprio(1);
        #pragma unroll
        for (int ks = 0; ks < 2; ++ks) {
            const int jbl = ks * 4 + fk;
            const int sb  = ((jbl ^ (fr & 7)) << 3);
            short8 aF0 = *(const short8*)&Ps[fr * 64 + sb];
            short8 aF1 = *(const short8*)&Ps[(16 + fr) * 64 + sb];
            short8 bF0 = *(const short8*)&Bs[(w * 32 + fr) * 64 + sb];
            short8 bF1 = *(const short8*)&Bs[(w * 32 + 16 + fr) * 64 + sb];
            acc00 = __builtin_amdgcn_mfma_f32_16x16x32_bf16(aF0, bF0, acc00, 0, 0, 0);
            acc01 = __builtin_amdgcn_mfma_f32_16x16x32_bf16(aF0, bF1, acc01, 0, 0, 0);
            acc10 = __builtin_amdgcn_mfma_f32_16x16x32_bf16(aF1, bF0, acc10, 0, 0, 0);
            acc11 = __builtin_amdgcn_mfma_f32_16x16x32_bf16(aF1, bF1, acc11, 0, 0, 0);
        }
        __builtin_amdgcn_s_setprio(0);
    }

    // row-sum: 8 threads per row (pjb), xor-reduce within the 8-lane group
    {
        float v = s_part;
        v += __shfl_xor(v, 1); v += __shfl_xor(v, 2); v += __shfl_xor(v, 4);
        if ((tid & 7) == 0) Srow[prow] = v;
    }
    __syncthreads();
    if (tid < 32) {
        float st = Srow[tid];
        if (DIRECT) Sred[tid] = 1.0f / st;
        else        pS[(size_t)(b * S + split) * NN + i0 + tid] = st;
    }
    __syncthreads();

    #pragma unroll
    for (int it = 0; it < 2; ++it) {
        #pragma unroll
        for (int dt = 0; dt < 2; ++dt) {
            f32x4 av = (it == 0) ? (dt == 0 ? acc00 : acc01)
                                 : (dt == 0 ? acc10 : acc11);
            #pragma unroll
            for (int r = 0; r < 4; ++r) {
                int i = it * 16 + fk * 4 + r;
                int d = w * 32 + dt * 16 + fr;
                if (DIRECT) {
                    float hv = av[r] * Sred[i];
                    hv = (hv > 0.f) ? hv : expm1f(hv);
                    out[((size_t)(b * NN) + i0 + i) * DD + d] = hv;
                } else {
                    pPV[((size_t)(b * S + split) * NN + i0 + i) * DD + d] = av[r];
                }
            }
        }
    }
}

// ---------------- Kernel D: combine splits, normalize, elu
template<int S>
__global__ __launch_bounds__(256) void reduce_kernel(
    const float* __restrict__ pPV, const float* __restrict__ pS,
    float* __restrict__ out)
{
    const int idx = blockIdx.x * 256 + threadIdx.x;   // (b,i,d4)
    const int bi = idx >> 5;
    const int d4 = (idx & 31) * 4;
    const int b  = bi >> 11;
    const int i  = bi & 2047;
    float4 sum = make_float4(0.f, 0.f, 0.f, 0.f);
    float ssum = 0.f;
    #pragma unroll
    for (int s = 0; s < S; ++s) {
        size_t base = (size_t)(b * S + s) * NN + i;
        float4 v = *(const float4*)&pPV[base * DD + d4];
        sum.x += v.x; sum.y += v.y; sum.z += v.z; sum.w += v.w;
        ssum  += pS[base];
    }
    float inv = 1.0f / ssum;
    float4 h;
    h.x = sum.x * inv; h.y = sum.y * inv; h.z = sum.z * inv; h.w = sum.w * inv;
    h.x = (h.x > 0.f) ? h.x : expm1f(h.x);
    h.y = (h.y > 0.f) ? h.y : expm1f(h.y);
    h.z = (h.z > 0.f) ? h.z : expm1f(h.z);
    h.w = (h.w > 0.f) ? h.w : expm1f(h.w);
    *(float4*)&out[(size_t)bi * DD + d4] = h;
}

extern "C" void kernel_launch(void* const* d_in, const int* in_sizes, int n_in,
                              void* d_out, int out_size, void* d_ws, size_t ws_size,
                              hipStream_t stream) {
    const float* x   = (const float*)d_in[0];
    const int*   adj = (const int*)d_in[1];
    const float* W   = (const float*)d_in[2];
    const float* a   = (const float*)d_in[3];
    float* out = (float*)d_out;

    unsigned short* WhbT = (unsigned short*)d_ws;                    // 4 MB
    float* f1 = (float*)((char*)d_ws + (4u << 20));                  // 64 KB
    float* f2 = f1 + BB * NN;                                        // 64 KB
    unsigned short* Whi = (unsigned short*)(f2 + BB * NN);           // 32 KB
    unsigned short* Wlo = Whi + DD * CC;                             // 32 KB
    float* pPV = (float*)(Wlo + DD * CC);

    const size_t base_bytes = (4u << 20) + (size_t)2 * BB * NN * 4 + (size_t)2 * DD * CC * 2;
    const size_t per_split  = (size_t)BB * NN * DD * 4 + (size_t)BB * NN * 4;

    wsplit_kernel<<<DD * CC / 256, 256, 0, stream>>>(W, Whi, Wlo);
    wh_kernel<<<dim3(NN / 64, BB), 256, 0, stream>>>(x, Whi, Wlo, a, WhbT, f1, f2);

    if (ws_size >= base_bytes + 4 * per_split) {
        constexpr int S = 4;
        float* pS = pPV + (size_t)S * BB * NN * DD;
        gat_kernel<S, false><<<dim3(NN / 32, S, BB), 256, 0, stream>>>(
            WhbT, adj, f1, f2, out, pPV, pS);
        reduce_kernel<S><<<BB * NN * DD / 4 / 256, 256, 0, stream>>>(pPV, pS, out);
    } else if (ws_size >= base_bytes + 2 * per_split) {
        constexpr int S = 2;
        float* pS = pPV + (size_t)S * BB * NN * DD;
        gat_kernel<S, false><<<dim3(NN / 32, S, BB), 256, 0, stream>>>(
            WhbT, adj, f1, f2, out, pPV, pS);
        reduce_kernel<S><<<BB * NN * DD / 4 / 256, 256, 0, stream>>>(pPV, pS, out);
    } else {
        gat_kernel<1, true><<<dim3(NN / 32, 1, BB), 256, 0, stream>>>(
            WhbT, adj, f1, f2, out, nullptr, nullptr);
    }
}

// Round 5
// 50.941 us; speedup vs baseline: 4.1571x; 1.1582x over previous
//
#include <hip/hip_runtime.h>
#include <hip/hip_bf16.h>
#include <math.h>

#define BB 8
#define NN 2048
#define CC 128
#define DD 128

typedef __attribute__((ext_vector_type(8))) short short8;
typedef __attribute__((ext_vector_type(4))) float f32x4;

static __device__ __forceinline__ unsigned short f2bf(float f) {
    __hip_bfloat16 h = __float2bfloat16(f);
    return *reinterpret_cast<unsigned short*>(&h);
}
static __device__ __forceinline__ float bf2f(unsigned short u) {
    __hip_bfloat16 h = *reinterpret_cast<__hip_bfloat16*>(&u);
    return __bfloat162float(h);
}

// ---------------- Kernel 0: split W into bf16 hi/lo
__global__ __launch_bounds__(256) void wsplit_kernel(
    const float* __restrict__ W,
    unsigned short* __restrict__ Whi, unsigned short* __restrict__ Wlo)
{
    int g = blockIdx.x * 256 + threadIdx.x;
    float w = W[g];
    unsigned short h = f2bf(w);
    Whi[g] = h;
    Wlo[g] = f2bf(w - bf2f(h));
}

// ---------------- Kernel A: Wh = x @ W^T via compensated MFMA.
// Writes WhbT bf16 [b][d][n], f1 (raw), E2=exp(f2), G2=exp(0.2 f2).
__global__ __launch_bounds__(256) void wh_kernel(
    const float* __restrict__ x,
    const unsigned short* __restrict__ Whi, const unsigned short* __restrict__ Wlo,
    const float* __restrict__ a,
    unsigned short* __restrict__ WhbT,
    float* __restrict__ f1, float* __restrict__ E2g, float* __restrict__ G2g)
{
    const int tid  = threadIdx.x;
    const int b    = blockIdx.y;
    const int n0   = blockIdx.x * 64;
    const int w    = tid >> 6;
    const int lane = tid & 63;
    const int fr   = lane & 15, fk = lane >> 4;
    const int n    = n0 + w * 16 + fr;

    short8 bh[4], bl[4];
    const float* xrow = &x[((size_t)(b * NN) + n) * CC];
    #pragma unroll
    for (int ks = 0; ks < 4; ++ks) {
        float xv[8];
        *(float4*)&xv[0] = *(const float4*)&xrow[(ks * 4 + fk) * 8];
        *(float4*)&xv[4] = *(const float4*)&xrow[(ks * 4 + fk) * 8 + 4];
        #pragma unroll
        for (int e = 0; e < 8; ++e) {
            unsigned short h = f2bf(xv[e]);
            bh[ks][e] = (short)h;
            bl[ks][e] = (short)f2bf(xv[e] - bf2f(h));
        }
    }

    f32x4 acc[8];
    #pragma unroll
    for (int dt = 0; dt < 8; ++dt) acc[dt] = (f32x4){0.f, 0.f, 0.f, 0.f};

    #pragma unroll
    for (int dt = 0; dt < 8; ++dt) {
        #pragma unroll
        for (int ks = 0; ks < 4; ++ks) {
            const int off = (dt * 16 + fr) * CC + (ks * 4 + fk) * 8;
            short8 aH = *(const short8*)&Whi[off];
            short8 aL = *(const short8*)&Wlo[off];
            acc[dt] = __builtin_amdgcn_mfma_f32_16x16x32_bf16(aH, bh[ks], acc[dt], 0, 0, 0);
            acc[dt] = __builtin_amdgcn_mfma_f32_16x16x32_bf16(aH, bl[ks], acc[dt], 0, 0, 0);
            acc[dt] = __builtin_amdgcn_mfma_f32_16x16x32_bf16(aL, bh[ks], acc[dt], 0, 0, 0);
        }
    }

    float p1 = 0.f, p2 = 0.f;
    #pragma unroll
    for (int dt = 0; dt < 8; ++dt) {
        #pragma unroll
        for (int r = 0; r < 4; ++r) {
            const int d = dt * 16 + fk * 4 + r;
            p1 += acc[dt][r] * a[d];
            p2 += acc[dt][r] * a[DD + d];
        }
    }
    p1 += __shfl_xor(p1, 16); p1 += __shfl_xor(p1, 32);
    p2 += __shfl_xor(p2, 16); p2 += __shfl_xor(p2, 32);
    if (fk == 0) {
        f1[b * NN + n]  = p1;
        E2g[b * NN + n] = __expf(p2);
        G2g[b * NN + n] = __expf(0.2f * p2);
    }

    #pragma unroll
    for (int dt = 0; dt < 8; ++dt) {
        #pragma unroll
        for (int r = 0; r < 4; ++r) {
            const int d = dt * 16 + fk * 4 + r;
            WhbT[((size_t)(b * 128 + d)) * NN + n] = f2bf(acc[dt][r]);
        }
    }
}

// ---------------- Kernel C: MFMA attention, 64 i-rows x 128 d, 8 waves.
// P weight = max(E1*E2, G1*G2)  ==  exp(leaky_relu(f1+f2))  (exact identity).
template<int S, bool DIRECT>
__global__ __launch_bounds__(512) void gat_kernel(
    const unsigned short* __restrict__ WhbT,   // [b][128 d][2048 n] bf16
    const int* __restrict__ adj,
    const float* __restrict__ f1,
    const float* __restrict__ E2g, const float* __restrict__ G2g,
    float* __restrict__ out,
    float* __restrict__ pPV, float* __restrict__ pS)
{
    constexpr int JS = NN / S;
    constexpr int NC = JS / 64;
    __shared__ __align__(16) unsigned short Bs[128 * 64];  // 16 KB
    __shared__ __align__(16) unsigned short Ps[64 * 64];   // 8 KB
    __shared__ float E2s[JS];
    __shared__ float G2s[JS];
    __shared__ float Srow[64];
    __shared__ float Sred[64];

    const int tid   = threadIdx.x;
    const int i0    = blockIdx.x * 64;
    const int split = blockIdx.y;
    const int b     = blockIdx.z;
    const int jBeg  = split * JS;

    // stage E2/G2 for this split once
    #pragma unroll
    for (int k = 0; k < JS / 512; ++k) {
        E2s[tid + 512 * k] = E2g[b * NN + jBeg + tid + 512 * k];
        G2s[tid + 512 * k] = G2g[b * NN + jBeg + tid + 512 * k];
    }

    // P role: row = tid>>3 (64 rows), 8 j-elems at pjb*8
    const int prow = tid >> 3;
    const int pjb  = tid & 7;
    const float f1r = f1[b * NN + i0 + prow];
    const float E1r = __expf(f1r);
    const float G1r = __expf(0.2f * f1r);
    const int psw = ((pjb ^ (prow & 7)) << 3);
    const int* adjP = adj + (size_t)(i0 + prow) * NN + jBeg + pjb * 8;

    // MFMA role: wave (wr,wc) in 2x4 -> rows wr*32+{0,16}, cols wc*32+{0,16}
    const int w    = tid >> 6;
    const int wr   = w >> 2, wc = w & 3;
    const int lane = tid & 63;
    const int fr   = lane & 15;
    const int fk   = lane >> 4;
    f32x4 acc00 = {0.f,0.f,0.f,0.f}, acc01 = {0.f,0.f,0.f,0.f};
    f32x4 acc10 = {0.f,0.f,0.f,0.f}, acc11 = {0.f,0.f,0.f,0.f};
    float s_part = 0.f;

    // B staging: 1024 x 16B loads, 2 per thread
    const size_t wbase = (size_t)b * 128 * NN;
    const int g0 = tid,       gd0 = g0 >> 3, gj0 = (g0 & 7) * 8;
    const int g1 = tid + 512, gd1 = g1 >> 3, gj1 = (g1 & 7) * 8;
    const int sw0 = gd0 * 64 + ((((g0) & 7) ^ (gd0 & 7)) << 3);
    const int sw1 = gd1 * 64 + ((((g1) & 7) ^ (gd1 & 7)) << 3);

    // prefetch chunk 0 B-tile
    uint4 br0 = *(const uint4*)&WhbT[wbase + (size_t)gd0 * NN + jBeg + gj0];
    uint4 br1 = *(const uint4*)&WhbT[wbase + (size_t)gd1 * NN + jBeg + gj1];

    __syncthreads();   // E2s/G2s ready

    for (int c = 0; c < NC; ++c) {
        // (B) compute P chunk: w = max(E1*E2, G1*G2), masked by adj
        int4 ad0 = *(const int4*)(adjP + c * 64);
        int4 ad1 = *(const int4*)(adjP + c * 64 + 4);
        float4 eA = *(const float4*)&E2s[c * 64 + pjb * 8];
        float4 eB = *(const float4*)&E2s[c * 64 + pjb * 8 + 4];
        float4 gA = *(const float4*)&G2s[c * 64 + pjb * 8];
        float4 gB = *(const float4*)&G2s[c * 64 + pjb * 8 + 4];
        float ev[8], gv[8]; int av[8];
        *(float4*)&ev[0] = eA; *(float4*)&ev[4] = eB;
        *(float4*)&gv[0] = gA; *(float4*)&gv[4] = gB;
        *(int4*)&av[0] = ad0;  *(int4*)&av[4] = ad1;
        unsigned short pks[8];
        float ssum = 0.f;
        #pragma unroll
        for (int e = 0; e < 8; ++e) {
            float m  = E1r * ev[e];
            float g  = G1r * gv[e];
            float wv = fmaxf(m, g);
            wv = (av[e] > 0) ? wv : 0.f;
            unsigned short bw = f2bf(wv);
            pks[e] = bw;
            ssum += bf2f(bw);
        }
        s_part += ssum;

        if (c > 0) __syncthreads();   // prev MFMA done reading LDS
        // (C) LDS writes
        *(uint4*)&Bs[sw0] = br0;
        *(uint4*)&Bs[sw1] = br1;
        {
            uint4 pv;
            pv.x = (unsigned int)pks[0] | ((unsigned int)pks[1] << 16);
            pv.y = (unsigned int)pks[2] | ((unsigned int)pks[3] << 16);
            pv.z = (unsigned int)pks[4] | ((unsigned int)pks[5] << 16);
            pv.w = (unsigned int)pks[6] | ((unsigned int)pks[7] << 16);
            *(uint4*)&Ps[prow * 64 + psw] = pv;
        }
        // (A) prefetch next chunk B-tile
        if (c + 1 < NC) {
            const int j0n = jBeg + (c + 1) * 64;
            br0 = *(const uint4*)&WhbT[wbase + (size_t)gd0 * NN + j0n + gj0];
            br1 = *(const uint4*)&WhbT[wbase + (size_t)gd1 * NN + j0n + gj1];
        }
        __syncthreads();   // tiles ready
        // (D) MFMA: 2x2 fragment tiles per wave
        __builtin_amdgcn_s_setprio(1);
        #pragma unroll
        for (int ks = 0; ks < 2; ++ks) {
            const int jbl = ks * 4 + fk;
            const int sb  = ((jbl ^ (fr & 7)) << 3);
            short8 aF0 = *(const short8*)&Ps[(wr * 32 + fr) * 64 + sb];
            short8 aF1 = *(const short8*)&Ps[(wr * 32 + 16 + fr) * 64 + sb];
            short8 bF0 = *(const short8*)&Bs[(wc * 32 + fr) * 64 + sb];
            short8 bF1 = *(const short8*)&Bs[(wc * 32 + 16 + fr) * 64 + sb];
            acc00 = __builtin_amdgcn_mfma_f32_16x16x32_bf16(aF0, bF0, acc00, 0, 0, 0);
            acc01 = __builtin_amdgcn_mfma_f32_16x16x32_bf16(aF0, bF1, acc01, 0, 0, 0);
            acc10 = __builtin_amdgcn_mfma_f32_16x16x32_bf16(aF1, bF0, acc10, 0, 0, 0);
            acc11 = __builtin_amdgcn_mfma_f32_16x16x32_bf16(aF1, bF1, acc11, 0, 0, 0);
        }
        __builtin_amdgcn_s_setprio(0);
    }

    // row-sum: 8 threads per row
    {
        float v = s_part;
        v += __shfl_xor(v, 1); v += __shfl_xor(v, 2); v += __shfl_xor(v, 4);
        if (pjb == 0) Srow[prow] = v;
    }
    __syncthreads();
    if (tid < 64) {
        float st = Srow[tid];
        if (DIRECT) Sred[tid] = 1.0f / st;
        else        pS[(size_t)(b * S + split) * NN + i0 + tid] = st;
    }
    __syncthreads();

    #pragma unroll
    for (int it = 0; it < 2; ++it) {
        #pragma unroll
        for (int dt = 0; dt < 2; ++dt) {
            f32x4 av = (it == 0) ? (dt == 0 ? acc00 : acc01)
                                 : (dt == 0 ? acc10 : acc11);
            #pragma unroll
            for (int r = 0; r < 4; ++r) {
                int i = wr * 32 + it * 16 + fk * 4 + r;
                int d = wc * 32 + dt * 16 + fr;
                if (DIRECT) {
                    float hv = av[r] * Sred[i];
                    hv = (hv > 0.f) ? hv : expm1f(hv);
                    out[((size_t)(b * NN) + i0 + i) * DD + d] = hv;
                } else {
                    pPV[((size_t)(b * S + split) * NN + i0 + i) * DD + d] = av[r];
                }
            }
        }
    }
}

// ---------------- Kernel D: combine splits, normalize, elu
template<int S>
__global__ __launch_bounds__(256) void reduce_kernel(
    const float* __restrict__ pPV, const float* __restrict__ pS,
    float* __restrict__ out)
{
    const int idx = blockIdx.x * 256 + threadIdx.x;
    const int bi = idx >> 5;
    const int d4 = (idx & 31) * 4;
    const int b  = bi >> 11;
    const int i  = bi & 2047;
    float4 sum = make_float4(0.f, 0.f, 0.f, 0.f);
    float ssum = 0.f;
    #pragma unroll
    for (int s = 0; s < S; ++s) {
        size_t base = (size_t)(b * S + s) * NN + i;
        float4 v = *(const float4*)&pPV[base * DD + d4];
        sum.x += v.x; sum.y += v.y; sum.z += v.z; sum.w += v.w;
        ssum  += pS[base];
    }
    float inv = 1.0f / ssum;
    float4 h;
    h.x = sum.x * inv; h.y = sum.y * inv; h.z = sum.z * inv; h.w = sum.w * inv;
    h.x = (h.x > 0.f) ? h.x : expm1f(h.x);
    h.y = (h.y > 0.f) ? h.y : expm1f(h.y);
    h.z = (h.z > 0.f) ? h.z : expm1f(h.z);
    h.w = (h.w > 0.f) ? h.w : expm1f(h.w);
    *(float4*)&out[(size_t)bi * DD + d4] = h;
}

extern "C" void kernel_launch(void* const* d_in, const int* in_sizes, int n_in,
                              void* d_out, int out_size, void* d_ws, size_t ws_size,
                              hipStream_t stream) {
    const float* x   = (const float*)d_in[0];
    const int*   adj = (const int*)d_in[1];
    const float* W   = (const float*)d_in[2];
    const float* a   = (const float*)d_in[3];
    float* out = (float*)d_out;

    unsigned short* WhbT = (unsigned short*)d_ws;                    // 4 MB
    float* f1  = (float*)((char*)d_ws + (4u << 20));                 // 64 KB
    float* E2g = f1 + BB * NN;                                       // 64 KB
    float* G2g = E2g + BB * NN;                                      // 64 KB
    unsigned short* Whi = (unsigned short*)(G2g + BB * NN);          // 32 KB
    unsigned short* Wlo = Whi + DD * CC;                             // 32 KB
    float* pPV = (float*)(Wlo + DD * CC);

    const size_t base_bytes = (4u << 20) + (size_t)3 * BB * NN * 4 + (size_t)2 * DD * CC * 2;
    const size_t per_split  = (size_t)BB * NN * DD * 4 + (size_t)BB * NN * 4;

    wsplit_kernel<<<DD * CC / 256, 256, 0, stream>>>(W, Whi, Wlo);
    wh_kernel<<<dim3(NN / 64, BB), 256, 0, stream>>>(x, Whi, Wlo, a, WhbT, f1, E2g, G2g);

    if (ws_size >= base_bytes + 4 * per_split) {
        constexpr int S = 4;
        float* pS = pPV + (size_t)S * BB * NN * DD;
        gat_kernel<S, false><<<dim3(NN / 64, S, BB), 512, 0, stream>>>(
            WhbT, adj, f1, E2g, G2g, out, pPV, pS);
        reduce_kernel<S><<<BB * NN * DD / 4 / 256, 256, 0, stream>>>(pPV, pS, out);
    } else if (ws_size >= base_bytes + 2 * per_split) {
        constexpr int S = 2;
        float* pS = pPV + (size_t)S * BB * NN * DD;
        gat_kernel<S, false><<<dim3(NN / 64, S, BB), 512, 0, stream>>>(
            WhbT, adj, f1, E2g, G2g, out, pPV, pS);
        reduce_kernel<S><<<BB * NN * DD / 4 / 256, 256, 0, stream>>>(pPV, pS, out);
    } else {
        gat_kernel<1, true><<<dim3(NN / 64, 1, BB), 512, 0, stream>>>(
            WhbT, adj, f1, E2g, G2g, out, nullptr, nullptr);
    }
}